// Round 3
// baseline (719.997 us; speedup 1.0000x reference)
//
#include <hip/hip_runtime.h>
#include <stdint.h>

#define N_PIX 401408
#define HWIMG 12544   // 112*112
#define LN_EPS 1e-5f

// ---------------- workspace layout ----------------
struct Ws {
  double R[3][8];          // sinkhorn row sums per iter, [iter][c*2+m]
  unsigned cnt4[4];        // class pixel counts (Bn)
  unsigned nmk[8];         // correct counts per (c,m)
  float  protoN[8][256];   // l2-normalized prototypes, row r = c*2+m
  float  fAcc[8][256];     // f accumulator
  float  ePack[N_PIX][2];  // per-pixel {sim[m=0,c], sim[m=1,c]} for c=label
  unsigned char flags[N_PIX];  // correct flag per pixel
};

// ---------------- reductions ----------------
__device__ __forceinline__ float wredf(float v) {   // full 64-lane
#pragma unroll
  for (int o = 32; o > 0; o >>= 1) v += __shfl_xor(v, o, 64);
  return v;
}
__device__ __forceinline__ double wredd(double v) {
#pragma unroll
  for (int o = 32; o > 0; o >>= 1) v += __shfl_xor(v, o, 64);
  return v;
}
__device__ __forceinline__ unsigned wredu(unsigned v) {
#pragma unroll
  for (int o = 32; o > 0; o >>= 1) v += (unsigned)__shfl_xor((int)v, o, 64);
  return v;
}

// ---------------- K0: init ws + normalize prototypes ----------------
__global__ __launch_bounds__(512) void k_init(const float* __restrict__ protos, Ws* __restrict__ ws) {
  int tid = threadIdx.x;
  if (tid < 24) ((double*)ws->R)[tid] = 0.0;
  if (tid >= 24 && tid < 32) ws->nmk[tid - 24] = 0u;
  if (tid >= 32 && tid < 36) ws->cnt4[tid - 32] = 0u;
  float* fa = &ws->fAcc[0][0];
  for (int i = tid; i < 8 * 256; i += 512) fa[i] = 0.f;

  int r = tid >> 6, lane = tid & 63;
  const float4 p = *(const float4*)(protos + r * 256 + lane * 4);
  float ss = p.x * p.x + p.y * p.y + p.z * p.z + p.w * p.w;
  ss = wredf(ss);
  float inv = 1.0f / fmaxf(sqrtf(ss), 1e-12f);
  float4 o; o.x = p.x * inv; o.y = p.y * inv; o.z = p.z * inv; o.w = p.w * inv;
  *(float4*)(&ws->protoN[r][lane * 4]) = o;
}

// ---------------- K1: per-pixel main ----------------
// 8 lanes per pixel (32 dims/lane), 8 pixels per wave, persistent blocks.
// Proto LDS layout: word s*260 + j*32 + q*4  (s = dim-slice 0..7, j = row).
// Bank of a read = (4s+4q) mod 32 -> the 8 distinct addresses per instr hit
// disjoint bank quads (conflict-free), 8-lane same-address broadcast.
__global__ __launch_bounds__(256) void k_main(
    const float* __restrict__ X, const int* __restrict__ label,
    const float* __restrict__ fng, const float* __restrict__ fnb,
    const float* __restrict__ mng, const float* __restrict__ mnb,
    Ws* __restrict__ ws,
    float* __restrict__ out_nearest, float* __restrict__ out_logits) {
  __shared__ float prS[8 * 260];
  __shared__ double sR[4][8];
  __shared__ unsigned sC[4][4];
  int tid = threadIdx.x;
  int wave = tid >> 6, lane = tid & 63;
  int s = lane & 7, g = lane >> 3;

  // stage normalized prototypes into skewed LDS (once per block)
  {
    int ps = tid >> 5, pj = (tid >> 2) & 7, ph = tid & 3;
    const float* src = &ws->protoN[pj][ps * 32 + ph * 8];
    float4 a = *(const float4*)src;
    float4 b = *(const float4*)(src + 4);
    float* dst = &prS[ps * 260 + pj * 32 + ph * 8];
    *(float4*)dst = a;
    *(float4*)(dst + 4) = b;
  }

  // trivial gamma/beta fast-path check (wave-uniform: every wave covers all dims)
  bool triv;
  {
    bool ok = true;
    const float* gp = fng + s * 32;
    const float* bp = fnb + s * 32;
#pragma unroll
    for (int q = 0; q < 8; q++) {
      float4 gq = *(const float4*)(gp + q * 4);
      float4 bq = *(const float4*)(bp + q * 4);
      ok = ok && gq.x == 1.f && gq.y == 1.f && gq.z == 1.f && gq.w == 1.f &&
           bq.x == 0.f && bq.y == 0.f && bq.z == 0.f && bq.w == 0.f;
    }
    triv = (bool)__all(ok);
  }
  float mngk = mng[s >> 1], mnbk = mnb[s >> 1];
  __syncthreads();

  double eAcc = 0.0;   // sinkhorn iter-1 row-sum contribution, bin = s
  unsigned cAcc = 0u;  // class count, bin = s (valid s<4)

  const int base = blockIdx.x * 256;
#pragma unroll 1
  for (int it = 0; it < 8; ++it) {
    int n = base + it * 32 + wave * 8 + g;
    const float* xb = X + (size_t)n * 256 + s * 32;
    float4 Y[8];
#pragma unroll
    for (int q = 0; q < 8; q++) Y[q] = *(const float4*)(xb + q * 4);
    int lab = label[n];

    float sm = 0.f, sq = 0.f;
#pragma unroll
    for (int q = 0; q < 8; q++) {
      sm += Y[q].x + Y[q].y + Y[q].z + Y[q].w;
      sq += Y[q].x * Y[q].x + Y[q].y * Y[q].y + Y[q].z * Y[q].z + Y[q].w * Y[q].w;
    }
    sm += __shfl_xor(sm, 1, 64); sq += __shfl_xor(sq, 1, 64);
    sm += __shfl_xor(sm, 2, 64); sq += __shfl_xor(sq, 2, 64);
    sm += __shfl_xor(sm, 4, 64); sq += __shfl_xor(sq, 4, 64);
    float mu = sm * (1.0f / 256.0f);
    float var = sq * (1.0f / 256.0f) - mu * mu;
    float rstd = rsqrtf(var + LN_EPS);

    if (triv) {
#pragma unroll
      for (int q = 0; q < 8; q++) {
        Y[q].x = (Y[q].x - mu) * rstd; Y[q].y = (Y[q].y - mu) * rstd;
        Y[q].z = (Y[q].z - mu) * rstd; Y[q].w = (Y[q].w - mu) * rstd;
      }
    } else {
      const float* gp = fng + s * 32;
      const float* bp = fnb + s * 32;
#pragma unroll
      for (int q = 0; q < 8; q++) {
        float4 gq = *(const float4*)(gp + q * 4);
        float4 bq = *(const float4*)(bp + q * 4);
        Y[q].x = (Y[q].x - mu) * rstd * gq.x + bq.x;
        Y[q].y = (Y[q].y - mu) * rstd * gq.y + bq.y;
        Y[q].z = (Y[q].z - mu) * rstd * gq.z + bq.z;
        Y[q].w = (Y[q].w - mu) * rstd * gq.w + bq.w;
      }
    }

    float qq = 0.f;
#pragma unroll
    for (int q = 0; q < 8; q++)
      qq += Y[q].x * Y[q].x + Y[q].y * Y[q].y + Y[q].z * Y[q].z + Y[q].w * Y[q].w;
    qq += __shfl_xor(qq, 1, 64);
    qq += __shfl_xor(qq, 2, 64);
    qq += __shfl_xor(qq, 4, 64);

    // 8 partial dots over this lane's 32 dims
    float dot[8];
#pragma unroll
    for (int j = 0; j < 8; j++) {
      const float* pj = &prS[s * 260 + j * 32];
      float acc = 0.f;
#pragma unroll
      for (int q = 0; q < 8; q++) {
        float4 pv = *(const float4*)(pj + q * 4);
        acc += Y[q].x * pv.x + Y[q].y * pv.y + Y[q].z * pv.z + Y[q].w * pv.w;
      }
      dot[j] = acc;
    }
    // packed butterfly: 7 shuffles, lane ends with full dot[s]
    bool b0 = (lane & 1) != 0;
    float e0, e1, e2, e3;
    {
      float t0 = b0 ? dot[0] : dot[1];
      float t1 = b0 ? dot[2] : dot[3];
      float t2 = b0 ? dot[4] : dot[5];
      float t3 = b0 ? dot[6] : dot[7];
      float r0 = __shfl_xor(t0, 1, 64);
      float r1 = __shfl_xor(t1, 1, 64);
      float r2 = __shfl_xor(t2, 1, 64);
      float r3 = __shfl_xor(t3, 1, 64);
      e0 = (b0 ? dot[1] : dot[0]) + r0;
      e1 = (b0 ? dot[3] : dot[2]) + r1;
      e2 = (b0 ? dot[5] : dot[4]) + r2;
      e3 = (b0 ? dot[7] : dot[6]) + r3;
    }
    bool b1 = (lane & 2) != 0;
    float f0, f1;
    {
      float t0 = b1 ? e0 : e1;
      float t1 = b1 ? e2 : e3;
      float r0 = __shfl_xor(t0, 2, 64);
      float r1 = __shfl_xor(t1, 2, 64);
      f0 = (b1 ? e1 : e0) + r0;
      f1 = (b1 ? e3 : e2) + r1;
    }
    bool b2 = (lane & 4) != 0;
    float dsum;
    {
      float t0 = b2 ? f0 : f1;
      float r0 = __shfl_xor(t0, 4, 64);
      dsum = (b2 ? f1 : f0) + r0;
    }
    float inv = 1.0f / fmaxf(sqrtf(qq), 1e-12f);
    float d = dsum * inv;   // sim for (k = s>>1, m = s&1) of this group's pixel

    out_logits[(size_t)n * 8 + ((s & 1) << 2) + (s >> 1)] = d;
    if ((s >> 1) == lab) ws->ePack[n][s & 1] = d;
    eAcc += ((s >> 1) == lab) ? (double)expf(d / 0.05f) : 0.0;
    cAcc += (s == lab) ? 1u : 0u;

    // nearest = max over m, then LN over the 4 classes
    float nm = fmaxf(d, __shfl_xor(d, 1, 64));
    float tA = __shfl_xor(nm, 2, 64);
    float s2 = nm + tA, qn = nm * nm + tA * tA;
    float s4 = s2 + __shfl_xor(s2, 4, 64);
    float q4 = qn + __shfl_xor(qn, 4, 64);
    float m4 = 0.25f * s4;
    float v4 = 0.25f * q4 - m4 * m4;
    float rs4 = rsqrtf(v4 + LN_EPS);
    int k = s >> 1;
    float lnv = (nm - m4) * rs4 * mngk + mnbk;
    int bimg = n / HWIMG;
    int p = n - bimg * HWIMG;
    if ((s & 1) == 0)
      out_nearest[((size_t)bimg * 4 + k) * HWIMG + p] = lnv;

    // argmax over k (tie -> lowest k)
    float av = lnv; int ak = k;
#pragma unroll
    for (int o = 2; o <= 4; o <<= 1) {
      float ov = __shfl_xor(av, o, 64);
      int ok2 = __shfl_xor(ak, o, 64);
      bool take = (ov > av) || (ov == av && ok2 < ak);
      av = take ? ov : av;
      ak = take ? ok2 : ak;
    }
    if (s == 0) ws->flags[n] = (lab == ak) ? (unsigned char)1 : (unsigned char)0;
  }

  // combine E / count bins across groups, then block, then global
  eAcc += __shfl_xor(eAcc, 8, 64);
  eAcc += __shfl_xor(eAcc, 16, 64);
  eAcc += __shfl_xor(eAcc, 32, 64);
  cAcc += (unsigned)__shfl_xor((int)cAcc, 8, 64);
  cAcc += (unsigned)__shfl_xor((int)cAcc, 16, 64);
  cAcc += (unsigned)__shfl_xor((int)cAcc, 32, 64);
  if (lane < 8) sR[wave][lane] = eAcc;
  if (lane < 4) sC[wave][lane] = cAcc;
  __syncthreads();
  if (tid < 8)
    unsafeAtomicAdd(&ws->R[0][tid], sR[0][tid] + sR[1][tid] + sR[2][tid] + sR[3][tid]);
  if (tid >= 8 && tid < 12) {
    int c = tid - 8;
    atomicAdd(&ws->cnt4[c], sC[0][c] + sC[1][c] + sC[2][c] + sC[3][c]);
  }
}

// ---------------- K2: sinkhorn reduction pass (iter = 2,3) ----------------
// (iter 1 fused into k_main; u-chain recomputed from R, identical float ops)
template <int ITER>
__global__ __launch_bounds__(256) void k_sink(const int* __restrict__ label,
                                              Ws* __restrict__ ws) {
  __shared__ float su1[8], su2[8], sBn[4];
  int tid = threadIdx.x;
  if (tid < 8) {
    int c = tid >> 1;
    float S = (float)ws->R[0][c * 2] + (float)ws->R[0][c * 2 + 1];
    float uu0 = 1.0f / fmaxf(S, 1e-30f);
    float R0 = (float)ws->R[0][tid];
    float uu1 = uu0 / (fmaxf(uu0 * R0, 1e-30f) * 2.0f);
    su1[tid] = uu1;
    if (ITER >= 3) {
      float R1 = (float)ws->R[1][tid];
      su2[tid] = uu1 / (fmaxf(uu1 * R1, 1e-30f) * 2.0f);
    }
  }
  if (tid < 4) sBn[tid] = fmaxf((float)ws->cnt4[tid], 1.0f);
  __syncthreads();

  double a0 = 0, a1 = 0, a2 = 0, a3 = 0, a4 = 0, a5 = 0, a6 = 0, a7 = 0;
  int gtid = blockIdx.x * 256 + tid;
  int T = gridDim.x * 256;
  for (int n = gtid; n < N_PIX; n += T) {
    int c = label[n];
    float2 e = *(const float2*)(&ws->ePack[n][0]);
    float E0 = expf(e.x / 0.05f);
    float E1 = expf(e.y / 0.05f);
    float S1 = su1[c * 2] * E0 + su1[c * 2 + 1] * E1;
    float v1 = 1.0f / (fmaxf(S1, 1e-30f) * sBn[c]);
    float v = v1;
    if (ITER >= 3) {
      float S2 = su2[c * 2] * E0 + su2[c * 2 + 1] * E1;
      v = v1 / (fmaxf(v1 * S2, 1e-30f) * sBn[c]);
    }
    double t0 = (double)(v * E0), t1 = (double)(v * E1);
    if (c == 0) { a0 += t0; a1 += t1; }
    else if (c == 1) { a2 += t0; a3 += t1; }
    else if (c == 2) { a4 += t0; a5 += t1; }
    else { a6 += t0; a7 += t1; }
  }
  a0 = wredd(a0); a1 = wredd(a1); a2 = wredd(a2); a3 = wredd(a3);
  a4 = wredd(a4); a5 = wredd(a5); a6 = wredd(a6); a7 = wredd(a7);
  __shared__ double lds[4][8];
  int wave = tid >> 6, lane = tid & 63;
  if (lane == 0) {
    lds[wave][0] = a0; lds[wave][1] = a1; lds[wave][2] = a2; lds[wave][3] = a3;
    lds[wave][4] = a4; lds[wave][5] = a5; lds[wave][6] = a6; lds[wave][7] = a7;
  }
  __syncthreads();
  if (tid < 8) {
    double ssum = lds[0][tid] + lds[1][tid] + lds[2][tid] + lds[3][tid];
    unsafeAtomicAdd(&ws->R[ITER - 1][tid], ssum);
  }
}

// ---------------- K3: proto_target + f / count accumulation ----------------
__global__ __launch_bounds__(256) void k_accum(
    const float* __restrict__ X, const int* __restrict__ label,
    const float* __restrict__ fng, const float* __restrict__ fnb,
    Ws* __restrict__ ws, float* __restrict__ out_target) {
  __shared__ float fa[4 * 2048];  // per-wave f accumulator copies (32 KB)
  __shared__ float su[8];
  __shared__ unsigned ldc[4][8];
  int tid = threadIdx.x;
  if (tid < 8) {
    int c = tid >> 1;
    float S = (float)ws->R[0][c * 2] + (float)ws->R[0][c * 2 + 1];
    float uu0 = 1.0f / fmaxf(S, 1e-30f);
    float R0 = (float)ws->R[0][tid];
    float uu1 = uu0 / (fmaxf(uu0 * R0, 1e-30f) * 2.0f);
    float R1 = (float)ws->R[1][tid];
    float uu2 = uu1 / (fmaxf(uu1 * R1, 1e-30f) * 2.0f);
    float R2 = (float)ws->R[2][tid];
    su[tid] = uu2 / (fmaxf(uu2 * R2, 1e-30f) * 2.0f);
  }
  for (int i = tid; i < 4 * 2048; i += 256) fa[i] = 0.f;
  __syncthreads();

  int wave = tid >> 6, lane = tid & 63;
  const float4 g4 = *(const float4*)(fng + lane * 4);
  const float4 b4 = *(const float4*)(fnb + lane * 4);
  float* myAcc = &fa[wave * 2048];

  unsigned cl[8] = {0, 0, 0, 0, 0, 0, 0, 0};
  int gw = blockIdx.x * 4 + wave;
  int GW = gridDim.x * 4;
  for (int ch = gw; ch < N_PIX / 64; ch += GW) {
    int n = ch * 64 + lane;
    int c = label[n];
    int fl = ws->flags[n];
    float2 e = *(const float2*)(&ws->ePack[n][0]);
    float E0 = expf(e.x / 0.05f);
    float E1 = expf(e.y / 0.05f);
    int idx = (su[c * 2 + 1] * E1 > su[c * 2] * E0) ? 1 : 0;
    out_target[n] = (float)(idx + 2 * c);
    int bucket = c * 2 + idx;
#pragma unroll
    for (int j = 0; j < 8; j++) cl[j] += (fl && bucket == j) ? 1u : 0u;

    unsigned long long mask = __ballot(fl);
    while (mask) {
      int src = __builtin_ctzll(mask);
      mask &= (mask - 1);
      int cc = __shfl(c, src, 64);
      int ii = __shfl(idx, src, 64);
      int nn = ch * 64 + src;
      const float4 x = *(const float4*)(X + (size_t)nn * 256 + lane * 4);
      float s = x.x + x.y + x.z + x.w;
      float q = x.x * x.x + x.y * x.y + x.z * x.z + x.w * x.w;
      s = wredf(s); q = wredf(q);
      float mu = s * (1.0f / 256.0f);
      float var = q * (1.0f / 256.0f) - mu * mu;
      float rstd = rsqrtf(var + LN_EPS);
      float y0 = (x.x - mu) * rstd * g4.x + b4.x;
      float y1 = (x.y - mu) * rstd * g4.y + b4.y;
      float y2 = (x.z - mu) * rstd * g4.z + b4.z;
      float y3 = (x.w - mu) * rstd * g4.w + b4.w;
      float qq = y0 * y0 + y1 * y1 + y2 * y2 + y3 * y3;
      qq = wredf(qq);
      float inv = 1.0f / fmaxf(sqrtf(qq), 1e-12f);
      float* dst = myAcc + (cc * 2 + ii) * 256 + lane * 4;
      dst[0] += y0 * inv; dst[1] += y1 * inv; dst[2] += y2 * inv; dst[3] += y3 * inv;
    }
  }
#pragma unroll
  for (int j = 0; j < 8; j++) cl[j] = wredu(cl[j]);
  if (lane == 0) {
#pragma unroll
    for (int j = 0; j < 8; j++) ldc[wave][j] = cl[j];
  }
  __syncthreads();
  float* fg = &ws->fAcc[0][0];
  for (int i = tid; i < 2048; i += 256) {
    float ssum = fa[i] + fa[2048 + i] + fa[4096 + i] + fa[6144 + i];
    unsafeAtomicAdd(fg + i, ssum);
  }
  if (tid < 8) {
    unsigned cs = ldc[0][tid] + ldc[1][tid] + ldc[2][tid] + ldc[3][tid];
    if (cs) atomicAdd(&ws->nmk[tid], cs);
  }
}

// ---------------- K4: finalize prototypes ----------------
__global__ __launch_bounds__(512) void k_final(Ws* __restrict__ ws, float* __restrict__ out_protos) {
  int tid = threadIdx.x;
  int r = tid >> 6, lane = tid & 63;
  const float4 f = *(const float4*)(&ws->fAcc[r][lane * 4]);
  float ss = wredf(f.x * f.x + f.y * f.y + f.z * f.z + f.w * f.w);
  float invf = 1.0f / fmaxf(sqrtf(ss), 1e-12f);
  unsigned nr = ws->nmk[r];
  int c = r >> 1;
  unsigned tot = ws->nmk[c * 2] + ws->nmk[c * 2 + 1];
  bool cond = (tot > 0u) && (nr != 0u);
  const float4 p = *(const float4*)(&ws->protoN[r][lane * 4]);
  float u0 = cond ? 0.999f * p.x + 0.001f * (f.x * invf) : p.x;
  float u1 = cond ? 0.999f * p.y + 0.001f * (f.y * invf) : p.y;
  float u2 = cond ? 0.999f * p.z + 0.001f * (f.z * invf) : p.z;
  float u3 = cond ? 0.999f * p.w + 0.001f * (f.w * invf) : p.w;
  float ss2 = wredf(u0 * u0 + u1 * u1 + u2 * u2 + u3 * u3);
  float invn = 1.0f / fmaxf(sqrtf(ss2), 1e-12f);
  float4 o; o.x = u0 * invn; o.y = u1 * invn; o.z = u2 * invn; o.w = u3 * invn;
  *(float4*)(out_protos + r * 256 + lane * 4) = o;
}

// ---------------- launch ----------------
extern "C" void kernel_launch(void* const* d_in, const int* in_sizes, int n_in,
                              void* d_out, int out_size, void* d_ws, size_t ws_size,
                              hipStream_t stream) {
  const float* X = (const float*)d_in[0];
  const int* label = (const int*)d_in[1];
  const float* protos = (const float*)d_in[2];
  const float* fng = (const float*)d_in[3];
  const float* fnb = (const float*)d_in[4];
  const float* mng = (const float*)d_in[5];
  const float* mnb = (const float*)d_in[6];

  float* out = (float*)d_out;
  float* out_nearest = out;                        // 32*4*12544 = 1605632
  float* out_logits = out + 1605632;               // N*8 = 3211264
  float* out_target = out_logits + 3211264;        // N
  float* out_protos = out_target + N_PIX;          // 2048
  Ws* ws = (Ws*)d_ws;

  k_init<<<1, 512, 0, stream>>>(protos, ws);
  k_main<<<N_PIX / 256, 256, 0, stream>>>(X, label, fng, fnb, mng, mnb, ws, out_nearest, out_logits);
  k_sink<2><<<512, 256, 0, stream>>>(label, ws);
  k_sink<3><<<512, 256, 0, stream>>>(label, ws);
  k_accum<<<1024, 256, 0, stream>>>(X, label, fng, fnb, ws, out_target);
  k_final<<<1, 512, 0, stream>>>(ws, out_protos);
}